// Round 5
// baseline (225.503 us; speedup 1.0000x reference)
//
#include <hip/hip_runtime.h>
#include <stdint.h>

typedef unsigned short u16;
typedef short short8 __attribute__((ext_vector_type(8)));
typedef short bh4 __attribute__((ext_vector_type(4)));
typedef float f32x4 __attribute__((ext_vector_type(4)));

// ---------- helpers ----------
__device__ __forceinline__ u16 f2bf_fast(float f) {  // round-half-up, 2 ops
  union { float f; uint32_t u; } x;
  x.f = f;
  return (u16)((x.u + 0x8000u) >> 16);
}

// pack two floats to bf16x2 (hi<<16 | lo): 2 adds + v_perm
__device__ __forceinline__ uint32_t pack2bf(float lo, float hi) {
  union { float f; uint32_t u; } a, b;
  a.f = lo; b.f = hi;
  return __builtin_amdgcn_perm(b.u + 0x8000u, a.u + 0x8000u, 0x07060302u);
}

__device__ __forceinline__ float bf2f(uint32_t u) {  // low 16 bits -> float
  union { uint32_t u; float f; } x;
  x.u = u << 16;
  return x.f;
}

__device__ __forceinline__ void gload_lds16(const void* g, void* l) {
  __builtin_amdgcn_global_load_lds(
      (const __attribute__((address_space(1))) void*)g,
      (__attribute__((address_space(3))) void*)l, 16, 0, 0);
}

__device__ __forceinline__ f32x4 mfma16(short8 a, short8 b, f32x4 c) {
  return __builtin_amdgcn_mfma_f32_16x16x32_bf16(a, b, c, 0, 0, 0);
}

// K=16 bf16 MFMA; device-pass builtin with host stub (host never runs it).
__device__ __forceinline__ f32x4 pv_mfma(bh4 a, bh4 b, f32x4 c) {
#if defined(__AMDGCN__) || defined(__HIP_DEVICE_COMPILE__)
  return __builtin_amdgcn_mfma_f32_16x16x16bf16_1k(a, b, c, 0, 0, 0);
#else
  (void)a; (void)b;
  return c;
#endif
}

// Q pre-scale: Hd^-0.5 * log2(e) so attention uses raw exp2
#define QSCALE 0.18033688011112042f

// ---------- fused cast fp32 -> bf16 ----------
__global__ void cast_all(const float* __restrict__ x, const float* __restrict__ wq,
                         const float* __restrict__ wk, const float* __restrict__ wv,
                         const float* __restrict__ wo, u16* __restrict__ dst) {
  const int b = blockIdx.x;
  const float* src;
  int boff;
  if (b < 4096)      { src = x;  boff = b; }
  else if (b < 5120) { src = wq; boff = b - 4096; }
  else if (b < 6144) { src = wk; boff = b - 5120; }
  else if (b < 7168) { src = wv; boff = b - 6144; }
  else               { src = wo; boff = b - 7168; }
  const int i = boff * 256 + threadIdx.x;
  float4 v = ((const float4*)src)[i];
  uint2 o;
  o.x = pack2bf(v.x, v.y);
  o.y = pack2bf(v.z, v.w);
  ((uint2*)dst)[b * 256 + threadIdx.x] = o;
}

// ---------- merged projection kernel (Q|K proj + V^T proj, one launch) ----------
// blocks 0..511:  C = x @ [Wq|Wk]^T : M=4096, N=2048, 128x128 tiles (16 bn x 32 bm)
//                 n<1024 -> Q (scaled, [B,H,S,Hd]); else K ([B,H,S,Hd]).
// blocks 512..767: C = Wv @ x^T     : M=1024(dout), N=4096(seq), (32 bn x 8 bm)
//                 out V^T [B,H,Hd,S].
// Single-buffered m97-style 2-barrier K-loop, 32 KB LDS, XOR-swizzled.
__global__ __launch_bounds__(256) void proj_qkv(
    const u16* __restrict__ xb, const u16* __restrict__ wqk,
    const u16* __restrict__ wv, const float* __restrict__ bq,
    const float* __restrict__ bk, const float* __restrict__ bv,
    u16* __restrict__ qw, u16* __restrict__ kw, u16* __restrict__ vw) {
  constexpr int K = 1024;
  __shared__ __align__(16) u16 Al[128 * 64];
  __shared__ __align__(16) u16 Bl[128 * 64];
  const int tid = threadIdx.x, lane = tid & 63, w = tid >> 6;
  const int quad = lane >> 4, l15 = lane & 15;
  const int wm = w >> 1, wn = w & 1;
  const bool isVT = (blockIdx.x >= 512);
  int bn, bm;
  const u16 *A, *Bt;
  if (!isVT) { bn = blockIdx.x & 15; bm = blockIdx.x >> 4; A = xb; Bt = wqk; }
  else { const int i = blockIdx.x - 512; bn = i & 31; bm = i >> 5; A = wv; Bt = xb; }
  const char* Ab = (const char*)(A + (size_t)bm * 128 * K);
  const char* Bb = (const char*)(Bt + (size_t)bn * 128 * K);

  f32x4 acc[4][4] = {};

  for (int k0 = 0; k0 < K; k0 += 64) {
#pragma unroll
    for (int i = 0; i < 4; ++i) {
      const int G = (w * 4 + i) * 64 + lane;
      const int row = G >> 3, sl = G & 7;
      gload_lds16(Ab + (size_t)row * 2048 + k0 * 2 + ((sl ^ (row & 7)) * 16),
                  &Al[G * 8]);
      gload_lds16(Bb + (size_t)row * 2048 + k0 * 2 + ((sl ^ (row & 7)) * 16),
                  &Bl[G * 8]);
    }
    __syncthreads();
#pragma unroll
    for (int kc = 0; kc < 2; ++kc) {
      short8 af[4], bf8[4];
#pragma unroll
      for (int mt = 0; mt < 4; ++mt)
        af[mt] = *(const short8*)&Al[(wm * 64 + mt * 16 + l15) * 64 +
                                     (((kc * 4 + quad) ^ (l15 & 7)) * 8)];
#pragma unroll
      for (int nt = 0; nt < 4; ++nt)
        bf8[nt] = *(const short8*)&Bl[(wn * 64 + nt * 16 + l15) * 64 +
                                      (((kc * 4 + quad) ^ (l15 & 7)) * 8)];
#pragma unroll
      for (int mt = 0; mt < 4; ++mt)
#pragma unroll
        for (int nt = 0; nt < 4; ++nt)
          acc[mt][nt] = mfma16(af[mt], bf8[nt], acc[mt][nt]);
    }
    __syncthreads();
  }

#pragma unroll
  for (int nt = 0; nt < 4; ++nt) {
    const int n = bn * 128 + wn * 64 + nt * 16 + l15;
#pragma unroll
    for (int mt = 0; mt < 4; ++mt) {
#pragma unroll
      for (int r = 0; r < 4; ++r) {
        const int m = bm * 128 + wm * 64 + mt * 16 + quad * 4 + r;
        const float a = acc[mt][nt][r];
        if (!isVT) {
          const bool isQ = (bn < 8);
          const int nn = isQ ? n : n - 1024;
          const float v = isQ ? (a + bq[nn]) * QSCALE : a + bk[nn];
          u16* op = isQ ? qw : kw;
          const int b = m >> 11, s = m & 2047, h = nn >> 6, d = nn & 63;
          op[((size_t)((b * 16 + h) * 2048 + s)) * 64 + d] = f2bf_fast(v);
        } else {
          const float v = a + bv[m];
          const int b = n >> 11, s = n & 2047;
          vw[((size_t)(b * 1024 + m)) * 2048 + s] = f2bf_fast(v);
        }
      }
    }
  }
}

// ---------- flash attention, transposed + key-split ----------
// grid (16 qt, 64): y = bh*2 + ks; each block does 1024 keys (16 x 64-key dbuf
// tiles), 128 q-rows, 4 waves (32 q-rows/wave, mt=2). 32 KB LDS: Q tile is
// overlaid on the kt=1 K/V buffers (dead until after the Q-frag hoist).
// Outputs UNNORMALIZED o-partials (bf16) + l-partials (f32); combine divides.
__global__ __launch_bounds__(256) void attn_kernel(
    const u16* __restrict__ Q, const u16* __restrict__ Kt,
    const u16* __restrict__ Vt, u16* __restrict__ op0, u16* __restrict__ op1,
    float* __restrict__ lp) {
  __shared__ __align__(16) u16 Sm[16384];  // 32 KB
  const int tid = threadIdx.x, lane = tid & 63, w = tid >> 6;
  const int quad = lane >> 4, l15 = lane & 15;
  const int qt = blockIdx.x;
  const int bh = blockIdx.y >> 1;
  const int ks = blockIdx.y & 1;

  const char* Qb = (const char*)(Q + ((size_t)bh * 2048 + qt * 128) * 64);
  const char* Kb = (const char*)(Kt + ((size_t)bh * 2048 + ks * 1024) * 64);
  const char* Vb = (const char*)(Vt + (size_t)bh * 64 * 2048 + ks * 1024);

  // LDS map: Kl[0]=Sm[0:4096], Kl[1]=Sm[4096:8192],
  //          Vl[0]=Sm[8192:12288], Vl[1]=Sm[12288:16384].
  // Ql overlay (prologue only): rows 0-63 -> Sm+4096, rows 64-127 -> Sm+12288.
  auto stageKV = [&](int kt, int b) {
    u16* Kl = Sm + b * 4096;
    u16* Vl = Sm + 8192 + b * 4096;
#pragma unroll
    for (int i = 0; i < 2; ++i) {
      const int G = (w * 2 + i) * 64 + lane;  // 0..511
      const int r = G >> 3, sl = G & 7;
      gload_lds16(Kb + (size_t)(kt * 64 + r) * 128 + ((sl ^ (r & 7)) * 16),
                  &Kl[G * 8]);
      gload_lds16(Vb + (size_t)r * 4096 + kt * 128 + ((sl ^ (r & 7)) * 16),
                  &Vl[G * 8]);
    }
  };

  // stage Q (split across the two kt=1 buffer regions) + first K/V tile
#pragma unroll
  for (int i = 0; i < 4; ++i) {
    const int G = (w * 4 + i) * 64 + lane;  // 0..1023; wave-uniform region
    const int row = G >> 3, sl = G & 7;
    u16* qdst = (G < 512) ? (Sm + 4096) : (Sm + 12288);
    gload_lds16(Qb + (size_t)row * 128 + ((sl ^ (row & 7)) * 16),
                &qdst[(G & 511) * 8]);
  }
  stageKV(0, 0);
  __syncthreads();  // all prologue staging landed

  // hoist Q fragments (wave w owns rows w*32..w*32+31)
  const u16* qreg = (w < 2) ? (Sm + 4096) : (Sm + 12288);
  const int qr0 = (w & 1) * 32;
  short8 aq[2][2];
#pragma unroll
  for (int mt = 0; mt < 2; ++mt)
#pragma unroll
    for (int kc = 0; kc < 2; ++kc)
      aq[mt][kc] = *(const short8*)&qreg[(qr0 + mt * 16 + l15) * 64 +
                                         (((kc * 4 + quad) ^ (l15 & 7)) * 8)];
  __syncthreads();  // hoists done before kt=1 staging overwrites Q regions

  f32x4 ot[4][2] = {};
  float lsum[2] = {};

  for (int kt = 0; kt < 16; ++kt) {
    const int buf = kt & 1;
    if (kt < 15) stageKV(kt + 1, buf ^ 1);  // prefetch overlaps compute
    const u16* Kl = Sm + buf * 4096;
    const u16* Vl = Sm + 8192 + buf * 4096;

    // S^T = K @ Q^T (64 keys x 32 qrows per wave)
    f32x4 st[2][4] = {};
#pragma unroll
    for (int kc = 0; kc < 2; ++kc)
#pragma unroll
      for (int ntk = 0; ntk < 4; ++ntk) {
        short8 kf = *(const short8*)&Kl[(ntk * 16 + l15) * 64 +
                                        (((kc * 4 + quad) ^ (l15 & 7)) * 8)];
        st[0][ntk] = mfma16(kf, aq[0][kc], st[0][ntk]);
        st[1][ntk] = mfma16(kf, aq[1][kc], st[1][ntk]);
      }

    // P^T = exp2(S^T) packed in-register into PV B-operands
    bh4 bp[2][4];
#pragma unroll
    for (int mt = 0; mt < 2; ++mt)
#pragma unroll
      for (int ntk = 0; ntk < 4; ++ntk) {
        const float e0 = __builtin_amdgcn_exp2f(st[mt][ntk][0]);
        const float e1 = __builtin_amdgcn_exp2f(st[mt][ntk][1]);
        const float e2 = __builtin_amdgcn_exp2f(st[mt][ntk][2]);
        const float e3 = __builtin_amdgcn_exp2f(st[mt][ntk][3]);
        lsum[mt] += (e0 + e1) + (e2 + e3);
        union { uint32_t u[2]; bh4 s; } pb;
        pb.u[0] = pack2bf(e0, e1);
        pb.u[1] = pack2bf(e2, e3);
        bp[mt][ntk] = pb.s;
      }

    // O^T += V^T @ P^T (V A-frags: b64, reused across mt)
#pragma unroll
    for (int ntk = 0; ntk < 4; ++ntk) {
      const int swz = ((ntk * 2 + (quad >> 1)) ^ (l15 & 7)) * 8 + (quad & 1) * 4;
#pragma unroll
      for (int ntd = 0; ntd < 4; ++ntd) {
        bh4 vf = *(const bh4*)&Vl[(ntd * 16 + l15) * 64 + swz];
        ot[ntd][0] = pv_mfma(vf, bp[0][ntk], ot[ntd][0]);
        ot[ntd][1] = pv_mfma(vf, bp[1][ntk], ot[ntd][1]);
      }
    }
    if (kt < 15) __syncthreads();  // buffer protection + prefetch drain
  }

  // epilogue: write unnormalized partials
  u16* op = ks ? op1 : op0;
#pragma unroll
  for (int mt = 0; mt < 2; ++mt) {
    float l = lsum[mt];
    l += __shfl_xor(l, 16);
    l += __shfl_xor(l, 32);
    const int row = qt * 128 + w * 32 + mt * 16 + l15;
    if (quad == 0) lp[((size_t)(ks * 32 + bh)) * 2048 + row] = l;
    u16* orow = op + ((size_t)bh * 2048 + row) * 64;
#pragma unroll
    for (int ntd = 0; ntd < 4; ++ntd) {
      uint2 ov;
      ov.x = pack2bf(ot[ntd][mt][0], ot[ntd][mt][1]);
      ov.y = pack2bf(ot[ntd][mt][2], ot[ntd][mt][3]);
      *(uint2*)(orow + ntd * 16 + quad * 4) = ov;
    }
  }
}

// ---------- combine: aw = (o0+o1)/(l0+l1), bf16 out [B,S,H*64] ----------
__global__ void attn_combine(const u16* __restrict__ op0,
                             const u16* __restrict__ op1,
                             const float* __restrict__ lp,
                             u16* __restrict__ aw) {
  const int idx = blockIdx.x * 256 + threadIdx.x;  // 1M threads, 4 elems each
  const int rowIdx = idx >> 4;                     // bh*2048 + s
  const int d4 = idx & 15;
  const int bh = rowIdx >> 11, s = rowIdx & 2047;
  const uint2 a0 = ((const uint2*)op0)[idx];
  const uint2 a1 = ((const uint2*)op1)[idx];
  const float inv = __builtin_amdgcn_rcpf(lp[rowIdx] + lp[rowIdx + 65536]);
  const float s0 = (bf2f(a0.x) + bf2f(a1.x)) * inv;
  const float s1 = (bf2f(a0.x >> 16) + bf2f(a1.x >> 16)) * inv;
  const float s2 = (bf2f(a0.y) + bf2f(a1.y)) * inv;
  const float s3 = (bf2f(a0.y >> 16) + bf2f(a1.y >> 16)) * inv;
  uint2 o;
  o.x = pack2bf(s0, s1);
  o.y = pack2bf(s2, s3);
  const size_t aidx = (((size_t)(bh >> 4) * 2048 + s) * 1024 +
                       (bh & 15) * 64 + d4 * 4) >> 2;
  ((uint2*)aw)[aidx] = o;
}

// ---------- out projection: C[4096,1024] f32 = aw @ Wo^T + bo ----------
// 128x64 tiles, single-buffered, 24 KB LDS, grid (16,32)=512.
__global__ __launch_bounds__(256) void gemm_out(const u16* __restrict__ A,
                                                const u16* __restrict__ Bt,
                                                const float* __restrict__ bias,
                                                float* __restrict__ out) {
  constexpr int K = 1024;
  __shared__ __align__(16) u16 Al[128 * 64];
  __shared__ __align__(16) u16 Bl[64 * 64];
  const int tid = threadIdx.x, lane = tid & 63, w = tid >> 6;
  const int quad = lane >> 4, l15 = lane & 15;
  const int wm = w >> 1, wn = w & 1;
  const int bm = blockIdx.y, bn = blockIdx.x;
  const char* Ab = (const char*)(A + (size_t)bm * 128 * K);
  const char* Bb = (const char*)(Bt + (size_t)bn * 64 * K);

  f32x4 acc[4][2] = {};

  for (int k0 = 0; k0 < K; k0 += 64) {
#pragma unroll
    for (int i = 0; i < 4; ++i) {
      const int G = (w * 4 + i) * 64 + lane;
      const int row = G >> 3, sl = G & 7;
      gload_lds16(Ab + (size_t)row * 2048 + k0 * 2 + ((sl ^ (row & 7)) * 16),
                  &Al[G * 8]);
    }
#pragma unroll
    for (int i = 0; i < 2; ++i) {
      const int G = (w * 2 + i) * 64 + lane;
      const int row = G >> 3, sl = G & 7;
      gload_lds16(Bb + (size_t)row * 2048 + k0 * 2 + ((sl ^ (row & 7)) * 16),
                  &Bl[G * 8]);
    }
    __syncthreads();
#pragma unroll
    for (int kc = 0; kc < 2; ++kc) {
      short8 af[4], bf8[2];
#pragma unroll
      for (int mt = 0; mt < 4; ++mt)
        af[mt] = *(const short8*)&Al[(wm * 64 + mt * 16 + l15) * 64 +
                                     (((kc * 4 + quad) ^ (l15 & 7)) * 8)];
#pragma unroll
      for (int nt = 0; nt < 2; ++nt)
        bf8[nt] = *(const short8*)&Bl[(wn * 32 + nt * 16 + l15) * 64 +
                                      (((kc * 4 + quad) ^ (l15 & 7)) * 8)];
#pragma unroll
      for (int mt = 0; mt < 4; ++mt)
#pragma unroll
        for (int nt = 0; nt < 2; ++nt)
          acc[mt][nt] = mfma16(af[mt], bf8[nt], acc[mt][nt]);
    }
    __syncthreads();
  }

#pragma unroll
  for (int nt = 0; nt < 2; ++nt) {
    const int n = bn * 64 + wn * 32 + nt * 16 + l15;
    const float bv = bias[n];
#pragma unroll
    for (int mt = 0; mt < 4; ++mt)
#pragma unroll
      for (int r = 0; r < 4; ++r) {
        const int m = bm * 128 + wm * 64 + mt * 16 + quad * 4 + r;
        out[(size_t)m * 1024 + n] = acc[mt][nt][r] + bv;
      }
  }
}

// ---------- launch ----------
extern "C" void kernel_launch(void* const* d_in, const int* in_sizes, int n_in,
                              void* d_out, int out_size, void* d_ws, size_t ws_size,
                              hipStream_t stream) {
  const float* x  = (const float*)d_in[0];
  const float* Wq = (const float*)d_in[1];
  const float* bq = (const float*)d_in[2];
  const float* Wk = (const float*)d_in[3];
  const float* bk = (const float*)d_in[4];
  const float* Wv = (const float*)d_in[5];
  const float* bv = (const float*)d_in[6];
  const float* Wo = (const float*)d_in[7];
  const float* bo = (const float*)d_in[8];

  const size_t M1 = 1024 * 1024;
  u16* xb  = (u16*)d_ws;          // 4M elems (dead after proj -> reused as op0)
  u16* wqb = xb + 4 * M1;         // wq|wk adjacent (fused proj)
  u16* wkb = wqb + M1;
  u16* wvb = wkb + M1;
  u16* wob = wvb + M1;
  u16* qw  = wob + M1;            // 4M each
  u16* kw  = qw + 4 * M1;
  u16* vw  = kw + 4 * M1;
  u16* aw  = vw + 4 * M1;         // ends at 24M elems
  u16* op0 = xb;                  // 4M elems, overlays dead xb
  u16* op1 = aw + 4 * M1;         // 24M..28M
  float* lp = (float*)(op1 + 4 * M1);  // 128K floats

  cast_all<<<8192, 256, 0, stream>>>(x, Wq, Wk, Wv, Wo, xb);

  proj_qkv<<<768, 256, 0, stream>>>(xb, wqb, wvb, bq, bk, bv, qw, kw, vw);

  attn_kernel<<<dim3(16, 64), 256, 0, stream>>>(qw, kw, vw, op0, op1, lp);

  attn_combine<<<4096, 256, 0, stream>>>(op0, op1, lp, aw);

  gemm_out<<<dim3(16, 32), 256, 0, stream>>>(aw, wob, bo, (float*)d_out);
}

// Round 6
// 208.645 us; speedup vs baseline: 1.0808x; 1.0808x over previous
//
#include <hip/hip_runtime.h>
#include <stdint.h>

typedef unsigned short u16;
typedef short short8 __attribute__((ext_vector_type(8)));
typedef short bh4 __attribute__((ext_vector_type(4)));
typedef float f32x4 __attribute__((ext_vector_type(4)));

// ---------- helpers ----------
__device__ __forceinline__ u16 f2bf_fast(float f) {
  union { float f; uint32_t u; } x;
  x.f = f;
  return (u16)((x.u + 0x8000u) >> 16);
}

__device__ __forceinline__ uint32_t pack2bf(float lo, float hi) {
  union { float f; uint32_t u; } a, b;
  a.f = lo; b.f = hi;
  return __builtin_amdgcn_perm(b.u + 0x8000u, a.u + 0x8000u, 0x07060302u);
}

__device__ __forceinline__ float bf2f(uint32_t u) {
  union { uint32_t u; float f; } x;
  x.u = u << 16;
  return x.f;
}

__device__ __forceinline__ void gload_lds16(const void* g, void* l) {
  __builtin_amdgcn_global_load_lds(
      (const __attribute__((address_space(1))) void*)g,
      (__attribute__((address_space(3))) void*)l, 16, 0, 0);
}

__device__ __forceinline__ f32x4 mfma16(short8 a, short8 b, f32x4 c) {
  return __builtin_amdgcn_mfma_f32_16x16x32_bf16(a, b, c, 0, 0, 0);
}

__device__ __forceinline__ f32x4 pv_mfma(bh4 a, bh4 b, f32x4 c) {
#if defined(__AMDGCN__) || defined(__HIP_DEVICE_COMPILE__)
  return __builtin_amdgcn_mfma_f32_16x16x16bf16_1k(a, b, c, 0, 0, 0);
#else
  (void)a; (void)b;
  return c;
#endif
}

// P32 packed fragment load: granule = ((tile*32+kc)*64+lane)*8 u16
__device__ __forceinline__ short8 ldfrag(const u16* base, int tile, int kc,
                                         int lane) {
  return *(const short8*)(base + ((((tile << 5) + kc) << 6) + lane) * 8);
}

#define QSCALE 0.18033688011112042f

// ---------- pack fp32 -> bf16 P32 fragment layout ----------
// P32: pack[((rt*32+kc)*64+ln)*8+j] = M[rt*16+(ln&15)][kc*32+(ln>>4)*8+j]
// rt 0..255 -> x (4096x1024) into xp; rt 256..511 -> [Wq;Wk;Wv;Wo] into wp.
__global__ void pack_all(const float* __restrict__ x, const float* __restrict__ wq,
                         const float* __restrict__ wk, const float* __restrict__ wv,
                         const float* __restrict__ wo, u16* __restrict__ xp,
                         u16* __restrict__ wp) {
  const int gi = blockIdx.x * 256 + threadIdx.x;  // granule id, 0..1048575
  const int lane = gi & 63;
  const int kc = (gi >> 6) & 31;
  const int rt = gi >> 11;  // row tile 0..511
  const int col = kc * 32 + (lane >> 4) * 8;
  const float* src;
  int row;
  if (rt < 256) {
    src = x;
    row = rt * 16 + (lane & 15);
  } else {
    const int wti = rt - 256;             // 0..255
    const int widx = wti >> 6;            // which weight
    src = (widx == 0) ? wq : (widx == 1) ? wk : (widx == 2) ? wv : wo;
    row = (wti & 63) * 16 + (lane & 15);
  }
  const float4* p = (const float4*)(src + (size_t)row * 1024 + col);
  const float4 v0 = p[0], v1 = p[1];
  uint4 o;
  o.x = pack2bf(v0.x, v0.y);
  o.y = pack2bf(v0.z, v0.w);
  o.z = pack2bf(v1.x, v1.y);
  o.w = pack2bf(v1.z, v1.w);
  u16* dst = (rt < 256) ? xp : wp;
  const int og = (rt < 256) ? gi : gi - 524288;
  ((uint4*)dst)[og] = o;
}

// ---------- LDS-free projection GEMM (QK + V^T merged) ----------
// 3072 waves of 64x64 tiles, no LDS, no barriers, register-dbuf K-loop.
// waves 0..2047:  C = x @ [Wq|Wk]^T : bn=gid>>6 (0..31), bm=gid&63.
//                 n<1024 -> Q (scaled) [B,H,S,Hd]; else K [B,H,S,Hd].
// waves 2048..3071: C = Wv @ x^T : bn=h&63 (seq), bm=h>>6 (dout/64).
//                 out V^T [B,H,Hd,S].
__global__ __launch_bounds__(256, 3) void proj_qkv(
    const u16* __restrict__ xp, const u16* __restrict__ wp,
    const float* __restrict__ bq, const float* __restrict__ bk,
    const float* __restrict__ bv, u16* __restrict__ qw, u16* __restrict__ kw,
    u16* __restrict__ vw) {
  const int gid = blockIdx.x * 4 + (threadIdx.x >> 6);
  const int lane = threadIdx.x & 63;
  const int quad = lane >> 4, l15 = lane & 15;
  const bool isQK = gid < 2048;
  int at0, bt0, bm, bn;
  const u16 *Ap, *Bp;
  if (isQK) {
    bn = gid >> 6; bm = gid & 63;
    Ap = xp; at0 = bm * 4;            // x row-tiles
    Bp = wp; bt0 = bn * 4;            // Wq|Wk tiles 0..127
  } else {
    const int h = gid - 2048;
    bn = h & 63; bm = h >> 6;
    Ap = wp; at0 = 128 + bm * 4;      // Wv tiles 128..191
    Bp = xp; bt0 = bn * 4;            // x row-tiles (seq)
  }

  f32x4 acc[4][4] = {};
  short8 af[2][4], bf[2][4];
#pragma unroll
  for (int mt = 0; mt < 4; ++mt) af[0][mt] = ldfrag(Ap, at0 + mt, 0, lane);
#pragma unroll
  for (int nt = 0; nt < 4; ++nt) bf[0][nt] = ldfrag(Bp, bt0 + nt, 0, lane);

#pragma unroll 4
  for (int kc = 0; kc < 32; ++kc) {
    const int cur = kc & 1, nxt = cur ^ 1;
    if (kc < 31) {
#pragma unroll
      for (int mt = 0; mt < 4; ++mt)
        af[nxt][mt] = ldfrag(Ap, at0 + mt, kc + 1, lane);
#pragma unroll
      for (int nt = 0; nt < 4; ++nt)
        bf[nxt][nt] = ldfrag(Bp, bt0 + nt, kc + 1, lane);
    }
#pragma unroll
    for (int mt = 0; mt < 4; ++mt)
#pragma unroll
      for (int nt = 0; nt < 4; ++nt)
        acc[mt][nt] = mfma16(af[cur][mt], bf[cur][nt], acc[mt][nt]);
  }

#pragma unroll
  for (int nt = 0; nt < 4; ++nt) {
    const int n = bn * 64 + nt * 16 + l15;
#pragma unroll
    for (int mt = 0; mt < 4; ++mt)
#pragma unroll
      for (int r = 0; r < 4; ++r) {
        const int m = bm * 64 + mt * 16 + quad * 4 + r;
        const float a = acc[mt][nt][r];
        if (isQK) {
          const bool isQ = (bn < 16);
          const int nn = isQ ? n : n - 1024;
          const float v = isQ ? (a + bq[nn]) * QSCALE : a + bk[nn];
          u16* op = isQ ? qw : kw;
          const int b = m >> 11, s = m & 2047, hh = nn >> 6, d = nn & 63;
          op[((size_t)((b * 16 + hh) * 2048 + s)) * 64 + d] = f2bf_fast(v);
        } else {
          const float v = a + bv[m];
          const int b = n >> 11, s = n & 2047;
          vw[((size_t)(b * 1024 + m)) * 2048 + s] = f2bf_fast(v);
        }
      }
  }
}

// ---------- flash attention, transposed + key-split (R5 structure) ----------
// Outputs o-partials DIRECTLY in P32-packed aw-shape (rows=b*2048+s, cols=h*64+d)
// + l-partials. Combine normalizes.
__global__ __launch_bounds__(256) void attn_kernel(
    const u16* __restrict__ Q, const u16* __restrict__ Kt,
    const u16* __restrict__ Vt, u16* __restrict__ op0, u16* __restrict__ op1,
    float* __restrict__ lp) {
  __shared__ __align__(16) u16 Sm[16384];  // 32 KB
  const int tid = threadIdx.x, lane = tid & 63, w = tid >> 6;
  const int quad = lane >> 4, l15 = lane & 15;
  const int qt = blockIdx.x;
  const int bh = blockIdx.y >> 1;
  const int ks = blockIdx.y & 1;

  const char* Qb = (const char*)(Q + ((size_t)bh * 2048 + qt * 128) * 64);
  const char* Kb = (const char*)(Kt + ((size_t)bh * 2048 + ks * 1024) * 64);
  const char* Vb = (const char*)(Vt + (size_t)bh * 64 * 2048 + ks * 1024);

  auto stageKV = [&](int kt, int b) {
    u16* Kl = Sm + b * 4096;
    u16* Vl = Sm + 8192 + b * 4096;
#pragma unroll
    for (int i = 0; i < 2; ++i) {
      const int G = (w * 2 + i) * 64 + lane;
      const int r = G >> 3, sl = G & 7;
      gload_lds16(Kb + (size_t)(kt * 64 + r) * 128 + ((sl ^ (r & 7)) * 16),
                  &Kl[G * 8]);
      gload_lds16(Vb + (size_t)r * 4096 + kt * 128 + ((sl ^ (r & 7)) * 16),
                  &Vl[G * 8]);
    }
  };

#pragma unroll
  for (int i = 0; i < 4; ++i) {
    const int G = (w * 4 + i) * 64 + lane;
    const int row = G >> 3, sl = G & 7;
    u16* qdst = (G < 512) ? (Sm + 4096) : (Sm + 12288);
    gload_lds16(Qb + (size_t)row * 128 + ((sl ^ (row & 7)) * 16),
                &qdst[(G & 511) * 8]);
  }
  stageKV(0, 0);
  __syncthreads();

  const u16* qreg = (w < 2) ? (Sm + 4096) : (Sm + 12288);
  const int qr0 = (w & 1) * 32;
  short8 aq[2][2];
#pragma unroll
  for (int mt = 0; mt < 2; ++mt)
#pragma unroll
    for (int kc = 0; kc < 2; ++kc)
      aq[mt][kc] = *(const short8*)&qreg[(qr0 + mt * 16 + l15) * 64 +
                                         (((kc * 4 + quad) ^ (l15 & 7)) * 8)];
  __syncthreads();

  f32x4 ot[4][2] = {};
  float lsum[2] = {};

  for (int kt = 0; kt < 16; ++kt) {
    const int buf = kt & 1;
    if (kt < 15) stageKV(kt + 1, buf ^ 1);
    const u16* Kl = Sm + buf * 4096;
    const u16* Vl = Sm + 8192 + buf * 4096;

    f32x4 st[2][4] = {};
#pragma unroll
    for (int kc = 0; kc < 2; ++kc)
#pragma unroll
      for (int ntk = 0; ntk < 4; ++ntk) {
        short8 kf = *(const short8*)&Kl[(ntk * 16 + l15) * 64 +
                                        (((kc * 4 + quad) ^ (l15 & 7)) * 8)];
        st[0][ntk] = mfma16(kf, aq[0][kc], st[0][ntk]);
        st[1][ntk] = mfma16(kf, aq[1][kc], st[1][ntk]);
      }

    bh4 bp[2][4];
#pragma unroll
    for (int mt = 0; mt < 2; ++mt)
#pragma unroll
      for (int ntk = 0; ntk < 4; ++ntk) {
        const float e0 = __builtin_amdgcn_exp2f(st[mt][ntk][0]);
        const float e1 = __builtin_amdgcn_exp2f(st[mt][ntk][1]);
        const float e2 = __builtin_amdgcn_exp2f(st[mt][ntk][2]);
        const float e3 = __builtin_amdgcn_exp2f(st[mt][ntk][3]);
        lsum[mt] += (e0 + e1) + (e2 + e3);
        union { uint32_t u[2]; bh4 s; } pb;
        pb.u[0] = pack2bf(e0, e1);
        pb.u[1] = pack2bf(e2, e3);
        bp[mt][ntk] = pb.s;
      }

#pragma unroll
    for (int ntk = 0; ntk < 4; ++ntk) {
      const int swz = ((ntk * 2 + (quad >> 1)) ^ (l15 & 7)) * 8 + (quad & 1) * 4;
#pragma unroll
      for (int ntd = 0; ntd < 4; ++ntd) {
        bh4 vf = *(const bh4*)&Vl[(ntd * 16 + l15) * 64 + swz];
        ot[ntd][0] = pv_mfma(vf, bp[0][ntk], ot[ntd][0]);
        ot[ntd][1] = pv_mfma(vf, bp[1][ntk], ot[ntd][1]);
      }
    }
    if (kt < 15) __syncthreads();
  }

  // epilogue: packed o-partials + l-partials
  const int b = bh >> 4, h = bh & 15;
  u16* op = ks ? op1 : op0;
#pragma unroll
  for (int mt = 0; mt < 2; ++mt) {
    float l = lsum[mt];
    l += __shfl_xor(l, 16);
    l += __shfl_xor(l, 32);
    const int srow = qt * 128 + w * 32 + mt * 16 + l15;
    if (quad == 0) lp[((size_t)(ks * 32 + bh)) * 2048 + srow] = l;
    const int rt = b * 128 + qt * 8 + w * 2 + mt;  // row tile (row = rt*16+l15)
#pragma unroll
    for (int ntd = 0; ntd < 4; ++ntd) {
      const int kc = h * 2 + (ntd >> 1);
      const int lnq = ((ntd & 1) * 2 + (quad >> 1)) & 3;
      const int j0 = (quad & 1) * 4;
      uint2 ov;
      ov.x = pack2bf(ot[ntd][mt][0], ot[ntd][mt][1]);
      ov.y = pack2bf(ot[ntd][mt][2], ot[ntd][mt][3]);
      *(uint2*)(op + ((size_t)((rt * 32 + kc) * 64 + lnq * 16 + l15)) * 8 + j0) = ov;
    }
  }
}

// ---------- combine (packed granule-wise): awp = (o0+o1)/(l0+l1) ----------
__global__ void attn_combine(const u16* __restrict__ op0,
                             const u16* __restrict__ op1,
                             const float* __restrict__ lp,
                             u16* __restrict__ awp) {
  const int g = blockIdx.x * 256 + threadIdx.x;  // granule 0..524287
  const int ln = g & 63;
  const int kc = (g >> 6) & 31;
  const int rt = g >> 11;
  const int row = rt * 16 + (ln & 15);
  const int b = row >> 11, s = row & 2047;
  const int h = kc >> 1;
  const int lidx = (b * 16 + h) * 2048 + s;
  const float inv = __builtin_amdgcn_rcpf(lp[lidx] + lp[lidx + 65536]);
  const uint4 a0 = ((const uint4*)op0)[g];
  const uint4 a1 = ((const uint4*)op1)[g];
  uint4 o;
  o.x = pack2bf((bf2f(a0.x) + bf2f(a1.x)) * inv,
                (bf2f(a0.x >> 16) + bf2f(a1.x >> 16)) * inv);
  o.y = pack2bf((bf2f(a0.y) + bf2f(a1.y)) * inv,
                (bf2f(a0.y >> 16) + bf2f(a1.y >> 16)) * inv);
  o.z = pack2bf((bf2f(a0.z) + bf2f(a1.z)) * inv,
                (bf2f(a0.z >> 16) + bf2f(a1.z >> 16)) * inv);
  o.w = pack2bf((bf2f(a0.w) + bf2f(a1.w)) * inv,
                (bf2f(a0.w >> 16) + bf2f(a1.w >> 16)) * inv);
  ((uint4*)awp)[g] = o;
}

// ---------- LDS-free out projection: C[4096,1024] f32 = aw @ Wo^T + bo ----------
// 2048 waves of 64x32 tiles: bm=gid&63, bnn=gid>>6 (0..31). Wo = wp tiles 192+.
__global__ __launch_bounds__(256, 3) void out_proj(const u16* __restrict__ awp,
                                                   const u16* __restrict__ wp,
                                                   const float* __restrict__ bo,
                                                   float* __restrict__ out) {
  const int gid = blockIdx.x * 4 + (threadIdx.x >> 6);
  const int lane = threadIdx.x & 63;
  const int quad = lane >> 4, l15 = lane & 15;
  const int bm = gid & 63, bnn = gid >> 6;
  const int at0 = bm * 4, bt0 = 192 + bnn * 2;

  f32x4 acc[4][2] = {};
  short8 af[2][4], bf[2][2];
#pragma unroll
  for (int mt = 0; mt < 4; ++mt) af[0][mt] = ldfrag(awp, at0 + mt, 0, lane);
#pragma unroll
  for (int nt = 0; nt < 2; ++nt) bf[0][nt] = ldfrag(wp, bt0 + nt, 0, lane);

#pragma unroll 4
  for (int kc = 0; kc < 32; ++kc) {
    const int cur = kc & 1, nxt = cur ^ 1;
    if (kc < 31) {
#pragma unroll
      for (int mt = 0; mt < 4; ++mt)
        af[nxt][mt] = ldfrag(awp, at0 + mt, kc + 1, lane);
#pragma unroll
      for (int nt = 0; nt < 2; ++nt)
        bf[nxt][nt] = ldfrag(wp, bt0 + nt, kc + 1, lane);
    }
#pragma unroll
    for (int mt = 0; mt < 4; ++mt)
#pragma unroll
      for (int nt = 0; nt < 2; ++nt)
        acc[mt][nt] = mfma16(af[cur][mt], bf[cur][nt], acc[mt][nt]);
  }

#pragma unroll
  for (int nt = 0; nt < 2; ++nt) {
    const int n = bnn * 32 + nt * 16 + l15;
    const float bb = bo[n];
#pragma unroll
    for (int mt = 0; mt < 4; ++mt)
#pragma unroll
      for (int r = 0; r < 4; ++r) {
        const int m = bm * 64 + mt * 16 + quad * 4 + r;
        out[(size_t)m * 1024 + n] = acc[mt][nt][r] + bb;
      }
  }
}

// ---------- launch ----------
extern "C" void kernel_launch(void* const* d_in, const int* in_sizes, int n_in,
                              void* d_out, int out_size, void* d_ws, size_t ws_size,
                              hipStream_t stream) {
  const float* x  = (const float*)d_in[0];
  const float* Wq = (const float*)d_in[1];
  const float* bq = (const float*)d_in[2];
  const float* Wk = (const float*)d_in[3];
  const float* bk = (const float*)d_in[4];
  const float* Wv = (const float*)d_in[5];
  const float* bv = (const float*)d_in[6];
  const float* Wo = (const float*)d_in[7];
  const float* bo = (const float*)d_in[8];

  const size_t M4 = (size_t)4 * 1024 * 1024;
  u16* xp  = (u16*)d_ws;     // 4M elems; dead after proj -> reused as op0
  u16* wp  = xp + M4;        // packed [Wq;Wk;Wv;Wo]
  u16* qw  = wp + M4;
  u16* kw  = qw + M4;
  u16* vw  = kw + M4;
  u16* op1 = vw + M4;
  u16* awp = op1 + M4;
  float* lp = (float*)(awp + M4);  // 128K floats
  u16* op0 = xp;

  pack_all<<<4096, 256, 0, stream>>>(x, Wq, Wk, Wv, Wo, xp, wp);

  proj_qkv<<<768, 256, 0, stream>>>(xp, wp, bq, bk, bv, qw, kw, vw);

  attn_kernel<<<dim3(16, 64), 256, 0, stream>>>(qw, kw, vw, op0, op1, lp);

  attn_combine<<<2048, 256, 0, stream>>>(op0, op1, lp, awp);

  out_proj<<<512, 256, 0, stream>>>(awp, wp, bo, (float*)d_out);
}